// Round 7
// baseline (285.360 us; speedup 1.0000x reference)
//
#include <hip/hip_runtime.h>
#include <math.h>

// LIF recurrence: v_t = v_{t-1}*decay*(1-z_{t-1}) + x_t ; z_t = (v_t > 0.3)
// x [B=128,T=2048,H=128] f32; out [B,T,H] f32 spikes.
//
// R7: single wave per block/CU does everything (no loader waves, no flags,
// no barriers). __launch_bounds__(64,1) -> VGPR budget 512, so a 2-tile
// register lookahead (A/B: 2 x 16 float4 = 128 VGPRs) is free. K-loop manually
// unrolled x2 for static A/B indexing. Per iteration: load tile k+2 -> regs;
// ds_write tile k+1 -> LDS (compiler inserts vmcnt(16): only tile k+1's loads
// drained, tile k+2's stay in flight); compute tile k from LDS; pack z bits
// into a 16 KB LDS bitplane. Phase 2: write-only expand to global.
// Steady outstanding reads: 16-32 KB/wave/CU.

constexpr int Bdim = 128;
constexpr int Tdim = 2048;
constexpr int Hdim = 128;
constexpr int HW   = 64;          // chains per block
constexpr int Ut   = 64;          // timesteps per tile (16 KB)
constexpr int NT   = Tdim / Ut;   // 32 tiles
constexpr float VTH = 0.3f;

__global__ __launch_bounds__(64, 1) void lif_kernel(
    const float* __restrict__ x,
    const float* __restrict__ v0,
    const float* __restrict__ z0,
    const float* __restrict__ decay_raw,
    float* __restrict__ out)
{
    __shared__ float    xslot[2][Ut][HW];        // 32 KB
    __shared__ unsigned zbits[Tdim / 32][HW];    // 16 KB bitplane

    const int lane = threadIdx.x;
    const int blk  = blockIdx.x;
    const int b    = blk >> 1;
    const int h0   = (blk & 1) * HW;

    const float* xbase = x   + (size_t)b * Tdim * Hdim + h0;
    float*       obase = out + (size_t)b * Tdim * Hdim + h0;
    // lane mapping (verified R2-R6): chunk j covers tile rows [4j,4j+4):
    // lane i -> row 4j+(i>>4), float col (i&15)*4.
    const int r_sub = lane >> 4;
    const int c_sub = (lane & 15) * 4;
    const int sub   = r_sub * Hdim + c_sub;

    const float decay = 1.0f / (1.0f + expf(-decay_raw[h0 + lane]));
    float v = v0[b * Hdim + h0 + lane];
    float z = z0[b * Hdim + h0 + lane];

    float4 A[16], B[16];

    auto loadT = [&](int tile, float4 (&buf)[16]) {
        const float* g = xbase + (size_t)tile * Ut * Hdim + sub;
        #pragma unroll
        for (int j = 0; j < 16; ++j)
            buf[j] = *(const float4*)(g + (size_t)(4 * j) * Hdim);
    };
    auto stageT = [&](int slot, float4 (&buf)[16]) {
        #pragma unroll
        for (int j = 0; j < 16; ++j)
            *(float4*)&xslot[slot][4 * j + r_sub][c_sub] = buf[j];
    };
    auto compT = [&](int k, int slot) {
        #pragma unroll
        for (int w = 0; w < 2; ++w) {
            unsigned mask = 0u;
            #pragma unroll
            for (int tb = 0; tb < 32; ++tb) {
                const float xv = xslot[slot][w * 32 + tb][lane];
                const float s  = v * decay + xv;     // same expr as R5/R6 (bit-exact)
                v = (z > 0.5f) ? xv : s;             // z=1 -> exactly x
                const bool sp = (v > VTH);
                z = sp ? 1.0f : 0.0f;
                mask |= (sp ? 1u : 0u) << tb;
            }
            zbits[k * 2 + w][lane] = mask;
        }
    };

    // prologue: tiles 0,1 in regs; tile 0 staged
    loadT(0, A);
    loadT(1, B);
    stageT(0, A);

    #pragma unroll 1
    for (int k = 0; k < NT; k += 2) {
        if (k + 2 < NT) loadT(k + 2, A);   // A free (its tile staged last iter)
        stageT(1, B);                      // tile k+1 -> slot1 (vmcnt(16) auto)
        compT(k, 0);                       // tile k from slot0
        if (k + 3 < NT) loadT(k + 3, B);
        if (k + 2 < NT) stageT(0, A);      // tile k+2 -> slot0
        compT(k + 1, 1);                   // tile k+1 from slot1
    }

    // ---------------- phase 2: write-only expand ----------------
    #pragma unroll 2
    for (int tw = 0; tw < Tdim / 32; ++tw) {
        const unsigned word = zbits[tw][lane];
        float* op = obase + (size_t)tw * 32 * Hdim + lane;
        #pragma unroll
        for (int tb = 0; tb < 32; ++tb)
            op[(size_t)tb * Hdim] = ((word >> tb) & 1u) ? 1.0f : 0.0f;
    }
}

extern "C" void kernel_launch(void* const* d_in, const int* in_sizes, int n_in,
                              void* d_out, int out_size, void* d_ws, size_t ws_size,
                              hipStream_t stream) {
    const float* x         = (const float*)d_in[0];
    const float* v0        = (const float*)d_in[1];
    const float* z0        = (const float*)d_in[2];
    const float* decay_raw = (const float*)d_in[3];
    float* out = (float*)d_out;

    lif_kernel<<<Bdim * Hdim / HW, 64, 0, stream>>>(x, v0, z0, decay_raw, out);
}